// Round 11
// baseline (78.739 us; speedup 1.0000x reference)
//
#include <hip/hip_runtime.h>

#define BB 32
#define NN 512
#define PP 128
#define MM (BB * NN)  // 16384 rows

typedef unsigned int u32;
typedef unsigned short u16;

typedef __attribute__((ext_vector_type(8))) short short8v;  // 8 bf16 (4 VGPR)
typedef __attribute__((ext_vector_type(4))) float f32x4;

// ---- ws layout ----
#define POSP_OFF 0                      // [8][MM] f32
#define NEGP_OFF (8 * MM)               // [8][MM] f32
#define UVB_OFF (16 * MM)               // u[128], v[128], bias[128]
#define PFIN_OFF (16 * MM + 512)        // pos final [MM]
#define NFIN_OFF (16 * MM + 512 + MM)   // neg final [MM]
// byte offsets (ws ~268 MB per 0xAA-fill evidence)
#define ADJB_OFF ((size_t)4194304)       // u16 [BB][NN][NN] = 16 MB
#define MUHI_OFF ((size_t)20971520)      // u16 [BB][NN][PP] = 4 MB (row-major)
#define MULO_OFF ((size_t)25165824)      // u16 [BB][NN][PP] = 4 MB
#define W2T_OFF ((size_t)29360128)       // u16 [PP][PP] = 32 KB (W2T[p][q]=bf16(W2[q][p]))
#define MW2HI_OFF ((size_t)29392896)     // u16 [BB][PP][NN] = 4 MB (muW2T hi)
#define MW2LO_OFF ((size_t)33587200)     // u16 [BB][PP][NN] = 4 MB (muW2T lo)

__device__ inline u32 bf16rne(float f) {
    u32 u = __float_as_uint(f);
    return (u + 0x7FFFu + ((u >> 16) & 1u)) >> 16;
}

// prep (r10 verbatim): pos/neg partials + adj as bf16.
__global__ __launch_bounds__(512) void k_prep(const float* __restrict__ weight,
                                              const float* __restrict__ adj,
                                              float* __restrict__ posP,
                                              float* __restrict__ negP,
                                              u16* __restrict__ adjb) {
    __shared__ float sps[8][128], sng[8][128];

    int b = blockIdx.z, seg = blockIdx.y;
    int tx = threadIdx.x;
    int jl2 = tx & 63;
    int g = tx >> 6;
    int j0tile = blockIdx.x * 128;
    int j = j0tile + jl2 * 2;

    size_t base = (size_t)b * NN * NN + ((size_t)seg * 64 + g * 8) * NN + j;
    const float2* wp = (const float2*)(weight + base);
    const float2* ap = (const float2*)(adj + base);
    u32* ab32 = (u32*)adjb + (base >> 1);
    float psx = 0.f, psy = 0.f, ngx = 0.f, ngy = 0.f;
#pragma unroll
    for (int k = 0; k < 8; ++k) {
        float2 a = ap[(size_t)k * (NN / 2)];
        float2 w = wp[(size_t)k * (NN / 2)];
        float wa0 = w.x * a.x;
        float wa1 = w.y * a.y;
        psx += fmaxf(wa0, 0.f);
        ngx += fmaxf(-wa0, 0.f);
        psy += fmaxf(wa1, 0.f);
        ngy += fmaxf(-wa1, 0.f);
        ab32[(size_t)k * (NN / 2)] =
            (a.x != 0.f ? 0x3F80u : 0u) | (a.y != 0.f ? 0x3F800000u : 0u);
    }
    sps[g][2 * jl2] = psx;
    sps[g][2 * jl2 + 1] = psy;
    sng[g][2 * jl2] = ngx;
    sng[g][2 * jl2 + 1] = ngy;
    __syncthreads();
    if (tx < 128) {
        float P = 0.f, Ng = 0.f;
#pragma unroll
        for (int g2 = 0; g2 < 8; ++g2) {
            P += sps[g2][tx];
            Ng += sng[g2][tx];
        }
        int row = b * NN + j0tile + tx;
        posP[seg * MM + row] = P;
        negP[seg * MM + row] = Ng;
    }
}

// aux: bid<64: mu -> hi/lo bf16 row-major (pure streaming); 64..71: pos/neg
// reduce; 72: uv+bias; 73: W2T bf16.
__global__ __launch_bounds__(256) void k_aux(
    const float* __restrict__ mu, const float* __restrict__ W2,
    const float* __restrict__ t4, const float* __restrict__ W3,
    const float* __restrict__ b1, const float* __restrict__ b2,
    const float* __restrict__ b3, const float* __restrict__ posP,
    const float* __restrict__ negP, float* __restrict__ posf,
    float* __restrict__ negf, float* __restrict__ uvb,
    u16* __restrict__ muhi, u16* __restrict__ mulo, u16* __restrict__ w2t) {
    __shared__ float su[2][PP], sv[2][PP];
    int bid = blockIdx.x;
    int t = threadIdx.x;
    if (bid < 64) {
        int gtid = bid * 256 + t;
        const float2* mu2 = (const float2*)mu;
        u32* hi32 = (u32*)muhi;
        u32* lo32 = (u32*)mulo;
#pragma unroll 8
        for (int s = 0; s < 64; ++s) {
            size_t idx = (size_t)s * 16384 + gtid;
            float2 v = mu2[idx];
            u32 h0 = bf16rne(v.x), h1 = bf16rne(v.y);
            float l0 = v.x - __uint_as_float(h0 << 16);
            float l1 = v.y - __uint_as_float(h1 << 16);
            hi32[idx] = h0 | (h1 << 16);
            lo32[idx] = bf16rne(l0) | (bf16rne(l1) << 16);
        }
    } else if (bid < 72) {
        int base = (bid - 64) * 2048;
#pragma unroll
        for (int rr = 0; rr < 8; ++rr) {
            int row = base + rr * 256 + t;
            float P = 0.f, Ng = 0.f;
#pragma unroll
            for (int s = 0; s < 8; ++s) {
                P += posP[s * MM + row];
                Ng += negP[s * MM + row];
            }
            posf[row] = P;
            negf[row] = Ng;
        }
    } else if (bid == 72) {
        int p = t & 127, h = t >> 7;
        float u = 0.f, v = 0.f;
#pragma unroll 8
        for (int q = h * 64; q < h * 64 + 64; ++q) {
            float tt = t4[q];
            float w = W3[q * PP + p];
            u += fmaxf(tt, 0.f) * w;
            v += fmaxf(-tt, 0.f) * w;
        }
        su[h][p] = u;
        sv[h][p] = v;
        __syncthreads();
        if (t < PP) {
            uvb[p] = su[0][p] + su[1][p];
            uvb[PP + p] = sv[0][p] + sv[1][p];
            uvb[2 * PP + p] = b1[p] + b2[p] + b3[p];
        }
    } else {
#pragma unroll 4
        for (int c = 0; c < 64; ++c) {
            int n = c * 256 + t;
            int q = n >> 7, pp = n & 127;
            w2t[pp * PP + q] = (u16)bf16rne(W2[q * PP + pp]);
        }
    }
}

// muw2: muW2T[p][i] = sum_q W2T[p][q] * mu[i][q] (hi+lo).  A = W2T (swizzled
// LDS, r10 phase-2 pattern), B = mu hi/lo from global. Output -> hi/lo bf16.
// 256 blocks = 32 b x 8 i-tiles(64); 256 thr = 4 waves; wave w: p-slice 32.
__global__ __launch_bounds__(256) void k_muw2(
    const u16* __restrict__ w2t, const u16* __restrict__ muhi,
    const u16* __restrict__ mulo, u16* __restrict__ mw2hi,
    u16* __restrict__ mw2lo) {
    __shared__ __align__(16) u16 w2L[PP * 128];  // 32 KB, XOR-swizzled cols

    int bid = blockIdx.x;
    int vbid = ((bid & 7) << 5) | (bid >> 3);  // XCD chunking
    int b = vbid >> 3;
    int i0 = (vbid & 7) * 64;
    int tx = threadIdx.x, lane = tx & 63, w = tx >> 6;

    {  // stage W2T swizzled (r10 phase-2 staging verbatim)
        int p = tx >> 1, qc = (tx & 1) * 64;
        const uint4* src = (const uint4*)(w2t + p * PP + qc);
#pragma unroll
        for (int c = 0; c < 8; ++c) {
            int q8 = (qc + c * 8) ^ ((p & 7) << 3);
            *(uint4*)&w2L[p * 128 + q8] = src[c];
        }
    }
    __syncthreads();

    const u16* mhB = muhi + (size_t)b * NN * PP;
    const u16* mlB = mulo + (size_t)b * NN * PP;

    f32x4 acc[2][4];  // [pt][it]
#pragma unroll
    for (int a = 0; a < 2; ++a)
#pragma unroll
        for (int c = 0; c < 4; ++c) acc[a][c] = (f32x4){0.f, 0.f, 0.f, 0.f};

#pragma unroll
    for (int ks = 0; ks < 4; ++ks) {
        int kb = ks * 32 + (lane >> 4) * 8;
        short8v afr[2];
#pragma unroll
        for (int pt = 0; pt < 2; ++pt) {
            int prow = w * 32 + pt * 16 + (lane & 15);
            afr[pt] = *(const short8v*)&w2L[prow * 128 + (kb ^ ((prow & 7) << 3))];
        }
#pragma unroll
        for (int it = 0; it < 4; ++it) {
            int irow = i0 + it * 16 + (lane & 15);
            short8v bh = *(const short8v*)&mhB[(size_t)irow * PP + kb];
            short8v bl = *(const short8v*)&mlB[(size_t)irow * PP + kb];
#pragma unroll
            for (int pt = 0; pt < 2; ++pt) {
                acc[pt][it] = __builtin_amdgcn_mfma_f32_16x16x32_bf16(afr[pt], bh, acc[pt][it], 0, 0, 0);
                acc[pt][it] = __builtin_amdgcn_mfma_f32_16x16x32_bf16(afr[pt], bl, acc[pt][it], 0, 0, 0);
            }
        }
    }

    // store: p = row (A), i = col (B); hi/lo split
#pragma unroll
    for (int pt = 0; pt < 2; ++pt)
#pragma unroll
        for (int it = 0; it < 4; ++it)
#pragma unroll
            for (int r = 0; r < 4; ++r) {
                int p = w * 32 + pt * 16 + (lane >> 4) * 4 + r;
                int i = i0 + it * 16 + (lane & 15);
                float v = acc[pt][it][r];
                u32 h = bf16rne(v);
                float lf = v - __uint_as_float(h << 16);
                size_t off = ((size_t)b * PP + p) * NN + i;
                mw2hi[off] = (u16)h;
                mw2lo[off] = (u16)bf16rne(lf);
            }
}

// fused: out = relu(adj @ muW2T(hi+lo) + x*W1 + pos*u + neg*v + bias).
// Single K=512 GEMM (r10 phase-1 staging/MFMA pattern) + r10 epilogue.
// 512 blocks = 32 b x 16 j-tiles(32); 256 thr = 4 waves; wave w: p-slice 32.
__global__ __launch_bounds__(256) void k_fused(
    const u16* __restrict__ adjb, const u16* __restrict__ mw2hi,
    const u16* __restrict__ mw2lo, const float* __restrict__ x,
    const float* __restrict__ W1, const float* __restrict__ posf,
    const float* __restrict__ negf, const float* __restrict__ uvb,
    float* __restrict__ out) {
    __shared__ __align__(16) u16 adjL[32 * 72];   // 4.5 KB
    __shared__ __align__(16) u16 mhiL[128 * 72];  // 18 KB
    __shared__ __align__(16) u16 mloL[128 * 72];  // 18 KB

    int bid = blockIdx.x;
    int vbid = ((bid & 7) << 6) | (bid >> 3);  // XCD chunking: 4 b's per XCD
    int b = vbid >> 4;
    int j0 = (vbid & 15) * 32;
    int tx = threadIdx.x, lane = tx & 63, w = tx >> 6;

    const u16* adjrow = adjb + ((size_t)b * NN + j0) * NN;
    const u16* mhG = mw2hi + (size_t)b * PP * NN;
    const u16* mlG = mw2lo + (size_t)b * PP * NN;

    f32x4 acc[2][2];  // [jt][pt]
#pragma unroll
    for (int a = 0; a < 2; ++a)
#pragma unroll
        for (int c = 0; c < 2; ++c) acc[a][c] = (f32x4){0.f, 0.f, 0.f, 0.f};

    for (int step = 0; step < 8; ++step) {
        int k0 = step * 64;
        {  // stage adj tile 32x64 (1 uint4/thread)
            int jj = tx >> 3, kk0 = (tx & 7) * 8;
            *(uint4*)&adjL[jj * 72 + kk0] =
                *(const uint4*)(adjrow + (size_t)jj * NN + k0 + kk0);
        }
        {  // stage muW2T hi/lo tiles 128x64 (r10 verbatim pattern)
            int p = tx >> 1, kk0 = (tx & 1) * 32;
            const uint4* sh = (const uint4*)(mhG + (size_t)p * NN + k0 + kk0);
            const uint4* sl = (const uint4*)(mlG + (size_t)p * NN + k0 + kk0);
#pragma unroll
            for (int c = 0; c < 4; ++c) {
                *(uint4*)&mhiL[p * 72 + kk0 + c * 8] = sh[c];
                *(uint4*)&mloL[p * 72 + kk0 + c * 8] = sl[c];
            }
        }
        __syncthreads();
#pragma unroll
        for (int ks = 0; ks < 2; ++ks) {
            int kb = ks * 32 + (lane >> 4) * 8;
            short8v afr[2];
#pragma unroll
            for (int jt = 0; jt < 2; ++jt)
                afr[jt] = *(const short8v*)&adjL[(jt * 16 + (lane & 15)) * 72 + kb];
#pragma unroll
            for (int pt = 0; pt < 2; ++pt) {
                int prow = w * 32 + pt * 16 + (lane & 15);
                short8v bh = *(const short8v*)&mhiL[prow * 72 + kb];
                short8v bl = *(const short8v*)&mloL[prow * 72 + kb];
#pragma unroll
                for (int jt = 0; jt < 2; ++jt) {
                    acc[jt][pt] = __builtin_amdgcn_mfma_f32_16x16x32_bf16(afr[jt], bh, acc[jt][pt], 0, 0, 0);
                    acc[jt][pt] = __builtin_amdgcn_mfma_f32_16x16x32_bf16(afr[jt], bl, acc[jt][pt], 0, 0, 0);
                }
            }
        }
        __syncthreads();
    }

    // epilogue (r10 verbatim form)
    float u_[2], v_[2], bb_[2], w1_[2];
#pragma unroll
    for (int pt = 0; pt < 2; ++pt) {
        int pp = w * 32 + pt * 16 + (lane & 15);
        u_[pt] = uvb[pp];
        v_[pt] = uvb[PP + pp];
        bb_[pt] = uvb[2 * PP + pp];
        w1_[pt] = W1[pp];
    }
    int row0 = b * NN + j0;
#pragma unroll
    for (int jt = 0; jt < 2; ++jt)
#pragma unroll
        for (int r = 0; r < 4; ++r) {
            int row = row0 + jt * 16 + (lane >> 4) * 4 + r;
            float xs = x[row];
            float ps = posf[row];
            float ng = negf[row];
#pragma unroll
            for (int pt = 0; pt < 2; ++pt) {
                int pp = w * 32 + pt * 16 + (lane & 15);
                float o = acc[jt][pt][r] + xs * w1_[pt] + ps * u_[pt] + ng * v_[pt] + bb_[pt];
                out[(size_t)row * PP + pp] = fmaxf(o, 0.f);
            }
        }
}

extern "C" void kernel_launch(void* const* d_in, const int* in_sizes, int n_in,
                              void* d_out, int out_size, void* d_ws, size_t ws_size,
                              hipStream_t stream) {
    const float* x      = (const float*)d_in[0];
    const float* mu     = (const float*)d_in[1];
    const float* weight = (const float*)d_in[2];
    const float* adj    = (const float*)d_in[3];
    const float* W1     = (const float*)d_in[4];
    const float* b1     = (const float*)d_in[5];
    const float* W2     = (const float*)d_in[6];
    const float* b2     = (const float*)d_in[7];
    const float* W3     = (const float*)d_in[8];
    const float* b3     = (const float*)d_in[9];
    const float* theta4 = (const float*)d_in[10];
    float* out = (float*)d_out;

    float* ws   = (float*)d_ws;
    float* posP = ws + POSP_OFF;
    float* negP = ws + NEGP_OFF;
    float* uvb  = ws + UVB_OFF;
    float* posf = ws + PFIN_OFF;
    float* negf = ws + NFIN_OFF;
    u16* adjb   = (u16*)((char*)d_ws + ADJB_OFF);
    u16* muhi   = (u16*)((char*)d_ws + MUHI_OFF);
    u16* mulo   = (u16*)((char*)d_ws + MULO_OFF);
    u16* w2t    = (u16*)((char*)d_ws + W2T_OFF);
    u16* mw2hi  = (u16*)((char*)d_ws + MW2HI_OFF);
    u16* mw2lo  = (u16*)((char*)d_ws + MW2LO_OFF);

    dim3 gp(NN / 128, 8, BB);
    k_prep<<<gp, 512, 0, stream>>>(weight, adj, posP, negP, adjb);

    k_aux<<<74, 256, 0, stream>>>(mu, W2, theta4, W3, b1, b2, b3, posP, negP,
                                  posf, negf, uvb, muhi, mulo, w2t);

    k_muw2<<<256, 256, 0, stream>>>(w2t, muhi, mulo, mw2hi, mw2lo);

    k_fused<<<512, 256, 0, stream>>>(adjb, mw2hi, mw2lo, x, W1, posf, negf,
                                     uvb, out);
}